// Round 1
// baseline (708.595 us; speedup 1.0000x reference)
//
#include <hip/hip_runtime.h>

#define NPTS 2048
#define NCH  256
#define CG   64    // channels per block
#define NI   83
#define NIP  84    // padded to multiple of 4
#define OD   256

__global__ __launch_bounds__(256) void sampler_fc_kernel(
    const float* __restrict__ points,
    const float* __restrict__ feat1,
    const float* __restrict__ feat2,
    const float* __restrict__ feat3,
    const float* __restrict__ fc_w,
    const float* __restrict__ fc_b,
    float* __restrict__ out)
{
    __shared__ int   sIdx[NI];
    __shared__ float P[CG * NIP];   // P[c_local][i], padded row

    const int bid = blockIdx.x;
    const int n   = bid >> 2;        // point index (consecutive blocks share a point -> gather locality)
    const int cg  = bid & 3;         // channel group
    const int tid = threadIdx.x;

    // ---- phase 1: per-point spatial indices (threads 0..82) ----
    if (tid < NI) {
        const float px = points[n * 2 + 0];
        const float py = points[n * 2 + 1];
        int i = tid;
        int k, Wl, j;
        if (i < 49)      { k = 7; Wl = 128; j = i; }
        else if (i < 74) { k = 5; Wl = 64;  j = i - 49; }
        else             { k = 3; Wl = 32;  j = i - 74; }
        const int   half = k >> 1;
        const float wm1  = (float)(Wl - 1);
        // x = clip(px*(W-1), 0, W-1)  (fp32, same as JAX)
        const float x = fminf(fmaxf(px * wm1, 0.f), wm1);
        const float y = fminf(fmaxf(py * wm1, 0.f), wm1);
        const float dx = (float)(j % k - half);   // fast-varying (tile)
        const float dy = (float)(j / k - half);   // slow-varying (repeat)
        // clip then truncate-to-int (values >= 0 so trunc == floor), matches astype(int32)
        const int ox = (int)fminf(fmaxf(x + dx, 0.f), wm1);
        const int oy = (int)fminf(fmaxf(y + dy, 0.f), wm1);
        sIdx[i] = oy * Wl + ox;
    }
    __syncthreads();

    // ---- phase 2: gather 64 channels x 83 samples into LDS ----
    for (int t = tid; t < CG * NIP; t += 256) {
        const int cl = t / NIP;
        const int i  = t - cl * NIP;
        float v = 0.f;
        if (i < NI) {
            const int cglob = cg * CG + cl;
            const float* base;
            int HW;
            if (i < 49)      { base = feat1; HW = 128 * 128; }
            else if (i < 74) { base = feat2; HW = 64 * 64; }
            else             { base = feat3; HW = 32 * 32; }
            v = base[(size_t)cglob * HW + sIdx[i]];
        }
        P[t] = v;   // pad slot (i==83) zeroed
    }
    __syncthreads();

    // ---- phase 3: FC. thread == output column o; FC row in registers ----
    const int o = tid;
    float w[NIP];
    #pragma unroll
    for (int i = 0; i < NI; ++i) w[i] = fc_w[o * NI + i];
    w[NI] = 0.f;
    const float b = fc_b[o];

    const float4* __restrict__ Pv = (const float4*)P;
    float* outp = out + ((size_t)(cg * CG) * NPTS + n) * OD + o;

    for (int cl = 0; cl < CG; ++cl) {
        float acc = b;
        #pragma unroll
        for (int ii = 0; ii < NIP / 4; ++ii) {
            const float4 p = Pv[cl * (NIP / 4) + ii];  // broadcast read, conflict-free
            acc += p.x * w[4 * ii + 0];
            acc += p.y * w[4 * ii + 1];
            acc += p.z * w[4 * ii + 2];
            acc += p.w * w[4 * ii + 3];
        }
        outp[(size_t)cl * NPTS * OD] = acc;   // coalesced 256-wide store
    }
}

extern "C" void kernel_launch(void* const* d_in, const int* in_sizes, int n_in,
                              void* d_out, int out_size, void* d_ws, size_t ws_size,
                              hipStream_t stream) {
    (void)in_sizes; (void)n_in; (void)out_size; (void)d_ws; (void)ws_size;
    const float* points = (const float*)d_in[0];
    const float* feat1  = (const float*)d_in[1];
    const float* feat2  = (const float*)d_in[2];
    const float* feat3  = (const float*)d_in[3];
    const float* fc_w   = (const float*)d_in[4];
    const float* fc_b   = (const float*)d_in[5];
    float* out = (float*)d_out;

    sampler_fc_kernel<<<NPTS * 4, 256, 0, stream>>>(points, feat1, feat2, feat3, fc_w, fc_b, out);
}

// Round 2
// 186.893 us; speedup vs baseline: 3.7915x; 3.7915x over previous
//
#include <hip/hip_runtime.h>

#define NPTS 2048
#define NCH  256
#define CG   64    // channels (M-rows) per block
#define NI   83    // true K
#define KP   96    // K padded to 3 * 32
#define PST  104   // LDS row stride in bf16 (pad: 208B rows -> ~2-way conflict, free)
#define OD   256

typedef __attribute__((ext_vector_type(8))) short bf16x8;   // 8 bf16 (4 VGPRs)
typedef __attribute__((ext_vector_type(4))) float f32x4;    // MFMA C/D

__device__ __forceinline__ unsigned short f32_to_bf16_rne(float f) {
    union { float f; unsigned int u; } cv; cv.f = f;
    unsigned int u = cv.u;
    u += 0x7fffu + ((u >> 16) & 1u);   // round-to-nearest-even (finite data)
    return (unsigned short)(u >> 16);
}

// ---- prep: lay fc_w out in bf16 B-fragment order into d_ws ----
// slot s = ct*192 + ks*64 + lane  (ct: 16 col-tiles, ks: 3 k-steps, lane: 0..63)
// lane's 8 values: col = ct*16 + (lane&15), k = ks*32 + (lane>>4)*8 + i
__global__ __launch_bounds__(256) void prep_w_kernel(
    const float* __restrict__ fc_w, unsigned short* __restrict__ wfrag)
{
    const int s = blockIdx.x * 256 + threadIdx.x;   // 0..3071
    const int ct   = s / 192;
    const int rem  = s - ct * 192;
    const int ks   = rem >> 6;
    const int lane = rem & 63;
    const int col  = ct * 16 + (lane & 15);
    const int k0   = ks * 32 + (lane >> 4) * 8;
    unsigned short v[8];
    #pragma unroll
    for (int i = 0; i < 8; ++i) {
        const int k = k0 + i;
        v[i] = (k < NI) ? f32_to_bf16_rne(fc_w[col * NI + k]) : (unsigned short)0;
    }
    // 16B contiguous store per slot
    ((bf16x8*)wfrag)[s] = *(const bf16x8*)v;
}

// ---- main: fused gather -> bf16 LDS -> MFMA FC -> fp32 store ----
__global__ __launch_bounds__(256) void sampler_fc_kernel(
    const float* __restrict__ points,
    const float* __restrict__ feat1,
    const float* __restrict__ feat2,
    const float* __restrict__ feat3,
    const unsigned short* __restrict__ wfrag,
    const float* __restrict__ fc_b,
    float* __restrict__ out)
{
    __shared__ int sIdx[NI];
    __shared__ __align__(16) unsigned short P[CG * PST];  // bf16 patches, padded rows

    const int bid = blockIdx.x;
    const int n   = bid >> 2;     // point index
    const int cg  = bid & 3;      // channel group
    const int tid = threadIdx.x;
    const int wv  = tid >> 6;     // wave 0..3 -> output cols [wv*64, wv*64+64)
    const int l   = tid & 63;

    // phase 1: spatial indices (identical math to the passing fp32 kernel)
    if (tid < NI) {
        const float px = points[n * 2 + 0];
        const float py = points[n * 2 + 1];
        int i = tid;
        int k, Wl, j;
        if (i < 49)      { k = 7; Wl = 128; j = i; }
        else if (i < 74) { k = 5; Wl = 64;  j = i - 49; }
        else             { k = 3; Wl = 32;  j = i - 74; }
        const int   half = k >> 1;
        const float wm1  = (float)(Wl - 1);
        const float x = fminf(fmaxf(px * wm1, 0.f), wm1);
        const float y = fminf(fmaxf(py * wm1, 0.f), wm1);
        const float dx = (float)(j % k - half);
        const float dy = (float)(j / k - half);
        const int ox = (int)fminf(fmaxf(x + dx, 0.f), wm1);
        const int oy = (int)fminf(fmaxf(y + dy, 0.f), wm1);
        sIdx[i] = oy * Wl + ox;
    }
    __syncthreads();

    // phase 2: gather 64 channels x 83 samples -> bf16 LDS (k padded to 96 with 0)
    for (int t = tid; t < CG * KP; t += 256) {
        const int cl = t / KP;
        const int i  = t - cl * KP;
        unsigned short v = 0;
        if (i < NI) {
            const int cglob = cg * CG + cl;
            const float* base;
            int HW;
            if (i < 49)      { base = feat1; HW = 128 * 128; }
            else if (i < 74) { base = feat2; HW = 64 * 64; }
            else             { base = feat3; HW = 32 * 32; }
            v = f32_to_bf16_rne(base[(size_t)cglob * HW + sIdx[i]]);
        }
        P[cl * PST + i] = v;
    }

    // B fragments for this wave: col-tiles ct_global = wv*4 + ctl, 3 k-steps each.
    // 16B/lane coalesced loads from the pre-swizzled table (L2-resident).
    bf16x8 bfr[4][3];
    #pragma unroll
    for (int ctl = 0; ctl < 4; ++ctl)
        #pragma unroll
        for (int ks = 0; ks < 3; ++ks) {
            const int s = ((wv * 4 + ctl) * 3 + ks) * 64 + l;
            bfr[ctl][ks] = ((const bf16x8*)wfrag)[s];
        }

    // bias for this lane's 4 col-tiles
    float bias[4];
    #pragma unroll
    for (int ctl = 0; ctl < 4; ++ctl)
        bias[ctl] = fc_b[wv * 64 + ctl * 16 + (l & 15)];

    f32x4 acc[4][4];
    #pragma unroll
    for (int rt = 0; rt < 4; ++rt)
        #pragma unroll
        for (int ctl = 0; ctl < 4; ++ctl)
            acc[rt][ctl] = (f32x4)(0.f);

    __syncthreads();

    // phase 3: MFMA. A fragment: row = rt*16 + (l&15), k = ks*32 + (l>>4)*8 (+0..7)
    #pragma unroll
    for (int ks = 0; ks < 3; ++ks) {
        bf16x8 afr[4];
        #pragma unroll
        for (int rt = 0; rt < 4; ++rt) {
            const int row = rt * 16 + (l & 15);
            const int kof = ks * 32 + ((l >> 4) << 3);
            afr[rt] = *(const bf16x8*)&P[row * PST + kof];
        }
        #pragma unroll
        for (int rt = 0; rt < 4; ++rt)
            #pragma unroll
            for (int ctl = 0; ctl < 4; ++ctl)
                acc[rt][ctl] = __builtin_amdgcn_mfma_f32_16x16x32_bf16(
                    afr[rt], bfr[ctl][ks], acc[rt][ctl], 0, 0, 0);
    }

    // epilogue: D lane layout col = l&15, row = (l>>4)*4 + j
    #pragma unroll
    for (int rt = 0; rt < 4; ++rt) {
        #pragma unroll
        for (int ctl = 0; ctl < 4; ++ctl) {
            const int col = wv * 64 + ctl * 16 + (l & 15);
            #pragma unroll
            for (int j = 0; j < 4; ++j) {
                const int row = rt * 16 + ((l >> 4) << 2) + j;
                const int c   = cg * CG + row;
                out[((size_t)c * NPTS + n) * OD + col] = acc[rt][ctl][j] + bias[ctl];
            }
        }
    }
}

extern "C" void kernel_launch(void* const* d_in, const int* in_sizes, int n_in,
                              void* d_out, int out_size, void* d_ws, size_t ws_size,
                              hipStream_t stream) {
    (void)in_sizes; (void)n_in; (void)out_size; (void)ws_size;
    const float* points = (const float*)d_in[0];
    const float* feat1  = (const float*)d_in[1];
    const float* feat2  = (const float*)d_in[2];
    const float* feat3  = (const float*)d_in[3];
    const float* fc_w   = (const float*)d_in[4];
    const float* fc_b   = (const float*)d_in[5];
    float* out = (float*)d_out;
    unsigned short* wfrag = (unsigned short*)d_ws;   // 48 KB fragment table

    prep_w_kernel<<<12, 256, 0, stream>>>(fc_w, wfrag);
    sampler_fc_kernel<<<NPTS * 4, 256, 0, stream>>>(
        points, feat1, feat2, feat3, wfrag, fc_b, out);
}

// Round 3
// 178.607 us; speedup vs baseline: 3.9673x; 1.0464x over previous
//
#include <hip/hip_runtime.h>

#define NPTS 2048
#define NCH  256
#define CG   64    // channels (N-cols of the GEMM) per block
#define NI   83    // true K
#define KP   96    // K padded to 3 * 32
#define PST  104   // LDS row stride in bf16 (208B rows -> 2-way conflict, free)
#define OD   256

// bf16 feature copies in d_ws, element offsets (ushorts) relative to featb base
#define WFRAG_SLOTS 3072
#define FEATB_OFF   24576          // ushorts: wfrag = 3072 slots * 8
#define F1_ELEMS    4194304        // 256*128*128
#define F2_ELEMS    1048576        // 256*64*64
#define F3_ELEMS    262144         // 256*32*32
#define F2_REL      4194304
#define F3_REL      5242880

typedef __attribute__((ext_vector_type(8))) short bf16x8;   // 8 bf16 (4 VGPRs)
typedef __attribute__((ext_vector_type(4))) float f32x4;    // MFMA C/D

__device__ __forceinline__ unsigned short f32_to_bf16_rne(float f) {
    union { float f; unsigned int u; } cv; cv.f = f;
    unsigned int u = cv.u;
    u += 0x7fffu + ((u >> 16) & 1u);
    return (unsigned short)(u >> 16);
}

// ---- prep 1: fc_w -> bf16 A-fragment table ----
// slot s = ot*192 + ks*64 + lane; lane's 8 vals: o = ot*16 + (l&15), k = ks*32 + (l>>4)*8 + i
__global__ __launch_bounds__(256) void prep_w_kernel(
    const float* __restrict__ fc_w, unsigned short* __restrict__ wfrag)
{
    const int s = blockIdx.x * 256 + threadIdx.x;   // 0..3071
    const int ot   = s / 192;
    const int rem  = s - ot * 192;
    const int ks   = rem >> 6;
    const int lane = rem & 63;
    const int o    = ot * 16 + (lane & 15);
    const int k0   = ks * 32 + (lane >> 4) * 8;
    unsigned short v[8];
    #pragma unroll
    for (int i = 0; i < 8; ++i) {
        const int k = k0 + i;
        v[i] = (k < NI) ? f32_to_bf16_rne(fc_w[o * NI + k]) : (unsigned short)0;
    }
    ((bf16x8*)wfrag)[s] = *(const bf16x8*)v;
}

// ---- prep 2: fp32 features -> bf16 copies (8 elems / thread) ----
__global__ __launch_bounds__(256) void prep_feat_kernel(
    const float* __restrict__ feat1, const float* __restrict__ feat2,
    const float* __restrict__ feat3, unsigned short* __restrict__ featb)
{
    const int s = blockIdx.x * 256 + threadIdx.x;   // 0..688127
    const float* src;
    size_t e;
    if (s < 524288)      { src = feat1; e = (size_t)s * 8; }
    else if (s < 655360) { src = feat2; e = (size_t)(s - 524288) * 8; featb += F2_REL; }
    else                 { src = feat3; e = (size_t)(s - 655360) * 8; featb += F3_REL; }
    const float4 a = ((const float4*)(src + e))[0];
    const float4 b = ((const float4*)(src + e))[1];
    unsigned short v[8];
    v[0] = f32_to_bf16_rne(a.x); v[1] = f32_to_bf16_rne(a.y);
    v[2] = f32_to_bf16_rne(a.z); v[3] = f32_to_bf16_rne(a.w);
    v[4] = f32_to_bf16_rne(b.x); v[5] = f32_to_bf16_rne(b.y);
    v[6] = f32_to_bf16_rne(b.z); v[7] = f32_to_bf16_rne(b.w);
    *(bf16x8*)(featb + e) = *(const bf16x8*)v;
}

// ---- main: gather(bf16) -> LDS -> MFMA (A=W, B=patches) -> nt fp32 store ----
__global__ __launch_bounds__(256) void sampler_fc_kernel(
    const float* __restrict__ points,
    const unsigned short* __restrict__ featb,
    const unsigned short* __restrict__ wfrag,
    const float* __restrict__ fc_b,
    float* __restrict__ out)
{
    __shared__ int sAddr[KP];            // elem offset (c=0) into featb
    __shared__ int sStep[KP];            // per-channel stride (HW), 0 for pad
    __shared__ __align__(16) unsigned short P[CG * PST];

    const int bid = blockIdx.x;
    const int n   = bid >> 2;
    const int cg  = bid & 3;
    const int tid = threadIdx.x;
    const int wv  = tid >> 6;            // wave -> o-range [wv*64, wv*64+64)
    const int l   = tid & 63;

    // phase 1: spatial indices -> (addr, step) tables
    if (tid < KP) {
        int addr = 0, step = 0;
        if (tid < NI) {
            const float px = points[n * 2 + 0];
            const float py = points[n * 2 + 1];
            int i = tid;
            int k, Wl, j, baseRel;
            if (i < 49)      { k = 7; Wl = 128; j = i;      baseRel = 0; }
            else if (i < 74) { k = 5; Wl = 64;  j = i - 49; baseRel = F2_REL; }
            else             { k = 3; Wl = 32;  j = i - 74; baseRel = F3_REL; }
            const int   half = k >> 1;
            const float wm1  = (float)(Wl - 1);
            const float x = fminf(fmaxf(px * wm1, 0.f), wm1);
            const float y = fminf(fmaxf(py * wm1, 0.f), wm1);
            const float dx = (float)(j % k - half);
            const float dy = (float)(j / k - half);
            const int ox = (int)fminf(fmaxf(x + dx, 0.f), wm1);
            const int oy = (int)fminf(fmaxf(y + dy, 0.f), wm1);
            addr = baseRel + oy * Wl + ox;
            step = Wl * Wl;
        }
        sAddr[tid] = addr;
        sStep[tid] = step;
    }
    __syncthreads();

    // phase 2: gather 64 channels x 83 bf16 samples -> LDS (padded with 0)
    for (int t = tid; t < CG * KP; t += 256) {
        const int cl = t / KP;
        const int i  = t - cl * KP;
        unsigned short v = 0;
        const int step = sStep[i];
        if (step != 0) {
            const int cglob = cg * CG + cl;
            v = featb[(size_t)(sAddr[i] + cglob * step)];
        }
        P[cl * PST + i] = v;
    }

    // A fragments (W) for this wave: 4 o-tiles x 3 k-steps, 16B/lane coalesced
    bf16x8 wfr[4][3];
    #pragma unroll
    for (int ot = 0; ot < 4; ++ot)
        #pragma unroll
        for (int ks = 0; ks < 3; ++ks)
            wfr[ot][ks] = ((const bf16x8*)wfrag)[((wv * 4 + ot) * 3 + ks) * 64 + l];

    // bias: lane's 4 consecutive o per o-tile
    float4 b4[4];
    #pragma unroll
    for (int ot = 0; ot < 4; ++ot)
        b4[ot] = *(const float4*)&fc_b[wv * 64 + ot * 16 + ((l >> 4) << 2)];

    f32x4 acc[4][4];
    #pragma unroll
    for (int ot = 0; ot < 4; ++ot)
        #pragma unroll
        for (int ct = 0; ct < 4; ++ct)
            acc[ot][ct] = (f32x4)(0.f);

    __syncthreads();

    // phase 3: MFMA. B fragment (patches): ch = ct*16 + (l&15), k = ks*32 + (l>>4)*8
    #pragma unroll
    for (int ks = 0; ks < 3; ++ks) {
        bf16x8 pfr[4];
        #pragma unroll
        for (int ct = 0; ct < 4; ++ct) {
            const int ch  = ct * 16 + (l & 15);
            const int kof = ks * 32 + ((l >> 4) << 3);
            pfr[ct] = *(const bf16x8*)&P[ch * PST + kof];
        }
        #pragma unroll
        for (int ot = 0; ot < 4; ++ot)
            #pragma unroll
            for (int ct = 0; ct < 4; ++ct)
                acc[ot][ct] = __builtin_amdgcn_mfma_f32_16x16x32_bf16(
                    wfr[ot][ks], pfr[ct], acc[ot][ct], 0, 0, 0);
    }

    // epilogue: D layout col = l&15 = channel, row = (l>>4)*4 + j = o (consecutive!)
    // -> one nontemporal dwordx4 per (ot, ct)
    #pragma unroll
    for (int ot = 0; ot < 4; ++ot) {
        const int o0 = wv * 64 + ot * 16 + ((l >> 4) << 2);
        #pragma unroll
        for (int ct = 0; ct < 4; ++ct) {
            const int c = cg * CG + ct * 16 + (l & 15);
            f32x4 v;
            #pragma unroll
            for (int j = 0; j < 4; ++j) v[j] = acc[ot][ct][j] + b4[ot][j];
            __builtin_nontemporal_store(v, (f32x4*)(out + ((size_t)c * NPTS + n) * OD + o0));
        }
    }
}

extern "C" void kernel_launch(void* const* d_in, const int* in_sizes, int n_in,
                              void* d_out, int out_size, void* d_ws, size_t ws_size,
                              hipStream_t stream) {
    (void)in_sizes; (void)n_in; (void)out_size; (void)ws_size;
    const float* points = (const float*)d_in[0];
    const float* feat1  = (const float*)d_in[1];
    const float* feat2  = (const float*)d_in[2];
    const float* feat3  = (const float*)d_in[3];
    const float* fc_w   = (const float*)d_in[4];
    const float* fc_b   = (const float*)d_in[5];
    float* out = (float*)d_out;

    unsigned short* wfrag = (unsigned short*)d_ws;
    unsigned short* featb = (unsigned short*)d_ws + FEATB_OFF;

    prep_w_kernel<<<12, 256, 0, stream>>>(fc_w, wfrag);
    prep_feat_kernel<<<2688, 256, 0, stream>>>(feat1, feat2, feat3, featb);
    sampler_fc_kernel<<<NPTS * 4, 256, 0, stream>>>(points, featb, wfrag, fc_b, out);
}

// Round 4
// 166.112 us; speedup vs baseline: 4.2658x; 1.0752x over previous
//
#include <hip/hip_runtime.h>

#define NPTS 2048
#define NCH  256
#define CG   64    // channels (N-cols of the GEMM) per block
#define NI   83    // true K
#define KP   96    // K padded to 3 * 32
#define PST  104   // LDS row stride in bf16 (208B rows -> 2-way conflict, free)
#define OD   256
#define SOR  260   // fp32 out-staging row stride (dwords): 260 % 32 == 4 -> benign

// d_ws layout (ushort elements): wfrag table then bf16 feature copies
#define FEATB_OFF   24576          // wfrag = 3072 slots * 8 ushorts
#define F2_REL      4194304        // 256*128*128
#define F3_REL      5242880        // + 256*64*64

typedef __attribute__((ext_vector_type(8))) short bf16x8;   // 8 bf16 (4 VGPRs)
typedef __attribute__((ext_vector_type(4))) float f32x4;    // MFMA C/D

__device__ __forceinline__ unsigned short f32_to_bf16_rne(float f) {
    union { float f; unsigned int u; } cv; cv.f = f;
    unsigned int u = cv.u;
    u += 0x7fffu + ((u >> 16) & 1u);
    return (unsigned short)(u >> 16);
}

// ---- prep 1: fc_w -> bf16 A-fragment table ----
// slot s = ot*192 + ks*64 + lane; lane's 8 vals: o = ot*16 + (l&15), k = ks*32 + (l>>4)*8 + i
__global__ __launch_bounds__(256) void prep_w_kernel(
    const float* __restrict__ fc_w, unsigned short* __restrict__ wfrag)
{
    const int s = blockIdx.x * 256 + threadIdx.x;   // 0..3071
    const int ot   = s / 192;
    const int rem  = s - ot * 192;
    const int ks   = rem >> 6;
    const int lane = rem & 63;
    const int o    = ot * 16 + (lane & 15);
    const int k0   = ks * 32 + (lane >> 4) * 8;
    unsigned short v[8];
    #pragma unroll
    for (int i = 0; i < 8; ++i) {
        const int k = k0 + i;
        v[i] = (k < NI) ? f32_to_bf16_rne(fc_w[o * NI + k]) : (unsigned short)0;
    }
    ((bf16x8*)wfrag)[s] = *(const bf16x8*)v;
}

// ---- prep 2: fp32 features -> bf16 copies (8 elems / thread) ----
__global__ __launch_bounds__(256) void prep_feat_kernel(
    const float* __restrict__ feat1, const float* __restrict__ feat2,
    const float* __restrict__ feat3, unsigned short* __restrict__ featb)
{
    const int s = blockIdx.x * 256 + threadIdx.x;   // 0..688127
    const float* src;
    size_t e;
    if (s < 524288)      { src = feat1; e = (size_t)s * 8; }
    else if (s < 655360) { src = feat2; e = (size_t)(s - 524288) * 8; featb += F2_REL; }
    else                 { src = feat3; e = (size_t)(s - 655360) * 8; featb += F3_REL; }
    const float4 a = ((const float4*)(src + e))[0];
    const float4 b = ((const float4*)(src + e))[1];
    unsigned short v[8];
    v[0] = f32_to_bf16_rne(a.x); v[1] = f32_to_bf16_rne(a.y);
    v[2] = f32_to_bf16_rne(a.z); v[3] = f32_to_bf16_rne(a.w);
    v[4] = f32_to_bf16_rne(b.x); v[5] = f32_to_bf16_rne(b.y);
    v[6] = f32_to_bf16_rne(b.z); v[7] = f32_to_bf16_rne(b.w);
    *(bf16x8*)(featb + e) = *(const bf16x8*)v;
}

// ---- main: gather(bf16) -> LDS -> MFMA (A=W, B=patches) -> LDS transpose -> 1KB NT stores ----
__global__ __launch_bounds__(256) void sampler_fc_kernel(
    const float* __restrict__ points,
    const unsigned short* __restrict__ featb,
    const unsigned short* __restrict__ wfrag,
    const float* __restrict__ fc_b,
    float* __restrict__ out)
{
    __shared__ int sAddr[KP];
    __shared__ int sStep[KP];
    // P (13312 B) and the 16x260 fp32 out-staging buffer (16640 B) are
    // time-disjoint: P dies at the last MFMA ds_read. Union them.
    __shared__ __align__(16) unsigned char smem[16 * SOR * 4];
    unsigned short* P    = (unsigned short*)smem;
    float*          Sout = (float*)smem;

    const int bid = blockIdx.x;
    const int n   = bid >> 2;
    const int cg  = bid & 3;
    const int tid = threadIdx.x;
    const int wv  = tid >> 6;            // wave -> o-range [wv*64, wv*64+64)
    const int l   = tid & 63;

    // phase 1: spatial indices -> (addr, step) tables
    if (tid < KP) {
        int addr = 0, step = 0;
        if (tid < NI) {
            const float px = points[n * 2 + 0];
            const float py = points[n * 2 + 1];
            int i = tid;
            int k, Wl, j, baseRel;
            if (i < 49)      { k = 7; Wl = 128; j = i;      baseRel = 0; }
            else if (i < 74) { k = 5; Wl = 64;  j = i - 49; baseRel = F2_REL; }
            else             { k = 3; Wl = 32;  j = i - 74; baseRel = F3_REL; }
            const int   half = k >> 1;
            const float wm1  = (float)(Wl - 1);
            const float x = fminf(fmaxf(px * wm1, 0.f), wm1);
            const float y = fminf(fmaxf(py * wm1, 0.f), wm1);
            const float dx = (float)(j % k - half);
            const float dy = (float)(j / k - half);
            const int ox = (int)fminf(fmaxf(x + dx, 0.f), wm1);
            const int oy = (int)fminf(fmaxf(y + dy, 0.f), wm1);
            addr = baseRel + oy * Wl + ox;
            step = Wl * Wl;
        }
        sAddr[tid] = addr;
        sStep[tid] = step;
    }
    __syncthreads();

    // phase 2: gather 64 channels x 83 bf16 samples -> LDS (padded with 0)
    for (int t = tid; t < CG * KP; t += 256) {
        const int cl = t / KP;
        const int i  = t - cl * KP;
        unsigned short v = 0;
        const int step = sStep[i];
        if (step != 0) {
            const int cglob = cg * CG + cl;
            v = featb[(size_t)(sAddr[i] + cglob * step)];
        }
        P[cl * PST + i] = v;
    }

    // A fragments (W): 4 o-tiles x 3 k-steps, 16B/lane coalesced, L2-resident
    bf16x8 wfr[4][3];
    #pragma unroll
    for (int ot = 0; ot < 4; ++ot)
        #pragma unroll
        for (int ks = 0; ks < 3; ++ks)
            wfr[ot][ks] = ((const bf16x8*)wfrag)[((wv * 4 + ot) * 3 + ks) * 64 + l];

    // bias: lane's 4 consecutive o per o-tile
    float4 b4[4];
    #pragma unroll
    for (int ot = 0; ot < 4; ++ot)
        b4[ot] = *(const float4*)&fc_b[wv * 64 + ot * 16 + ((l >> 4) << 2)];

    f32x4 acc[4][4];
    #pragma unroll
    for (int ot = 0; ot < 4; ++ot)
        #pragma unroll
        for (int ct = 0; ct < 4; ++ct)
            acc[ot][ct] = (f32x4)(0.f);

    __syncthreads();

    // phase 3: MFMA. B fragment (patches): ch = ct*16 + (l&15), k = ks*32 + (l>>4)*8
    #pragma unroll
    for (int ks = 0; ks < 3; ++ks) {
        bf16x8 pfr[4];
        #pragma unroll
        for (int ct = 0; ct < 4; ++ct) {
            const int ch  = ct * 16 + (l & 15);
            const int kof = ks * 32 + ((l >> 4) << 3);
            pfr[ct] = *(const bf16x8*)&P[ch * PST + kof];
        }
        #pragma unroll
        for (int ot = 0; ot < 4; ++ot)
            #pragma unroll
            for (int ct = 0; ct < 4; ++ct)
                acc[ot][ct] = __builtin_amdgcn_mfma_f32_16x16x32_bf16(
                    wfr[ot][ks], pfr[ct], acc[ot][ct], 0, 0, 0);
    }

    __syncthreads();   // all waves done reading P; smem can be reused

    // phase 4: epilogue via LDS transpose, 4 chunks of 16 channels.
    // D layout: lane holds o = wv*64 + ot*16 + (l>>4)*4 + j (consecutive),
    //           ch_local = ct*16 + (l&15).
    #pragma unroll
    for (int ct = 0; ct < 4; ++ct) {
        #pragma unroll
        for (int ot = 0; ot < 4; ++ot) {
            f32x4 v;
            #pragma unroll
            for (int j = 0; j < 4; ++j) v[j] = acc[ot][ct][j] + b4[ot][j];
            const int ch = l & 15;
            const int o  = wv * 64 + ot * 16 + ((l >> 4) << 2);
            *(f32x4*)&Sout[ch * SOR + o] = v;
        }
        __syncthreads();
        // each wave streams 4 whole rows: 64 lanes x 16B = 1KB contiguous NT burst
        #pragma unroll
        for (int r = 0; r < 4; ++r) {
            const int ch = wv * 4 + r;
            const int c  = cg * CG + ct * 16 + ch;
            const f32x4 v = *(const f32x4*)&Sout[ch * SOR + l * 4];
            __builtin_nontemporal_store(v, (f32x4*)(out + ((size_t)c * NPTS + n) * OD + l * 4));
        }
        __syncthreads();
    }
}

extern "C" void kernel_launch(void* const* d_in, const int* in_sizes, int n_in,
                              void* d_out, int out_size, void* d_ws, size_t ws_size,
                              hipStream_t stream) {
    (void)in_sizes; (void)n_in; (void)out_size; (void)ws_size;
    const float* points = (const float*)d_in[0];
    const float* feat1  = (const float*)d_in[1];
    const float* feat2  = (const float*)d_in[2];
    const float* feat3  = (const float*)d_in[3];
    const float* fc_w   = (const float*)d_in[4];
    const float* fc_b   = (const float*)d_in[5];
    float* out = (float*)d_out;

    unsigned short* wfrag = (unsigned short*)d_ws;
    unsigned short* featb = (unsigned short*)d_ws + FEATB_OFF;

    prep_w_kernel<<<12, 256, 0, stream>>>(fc_w, wfrag);
    prep_feat_kernel<<<2688, 256, 0, stream>>>(feat1, feat2, feat3, featb);
    sampler_fc_kernel<<<NPTS * 4, 256, 0, stream>>>(points, featb, wfrag, fc_b, out);
}